// Round 1
// baseline (2068.986 us; speedup 1.0000x reference)
//
#include <hip/hip_runtime.h>
#include <hip/hip_bf16.h>

#define EMBED 128
#define NRAD  16
#define OUTE  256

// ---------------------------------------------------------------------------
// Phase 1: per-edge RBF gate + scatter-add into per-particle accumulator.
// 32 threads per edge; each thread owns 4 consecutive embed columns and holds
// its W_rbf column slice (16 x float4 = 64 VGPRs) in registers for the whole
// grid-stride loop. rbf row (64 B) is re-read per 32-thread group -> L1 hit.
// ---------------------------------------------------------------------------
__global__ __launch_bounds__(256) void edge_scatter_kernel(
    const float* __restrict__ messages, const float* __restrict__ rbf,
    const int* __restrict__ idx_i, const float* __restrict__ W_rbf,
    float* __restrict__ summed, int n_edges)
{
    const int sub = threadIdx.x & 31;   // position within 32-thread edge group
    const int col = sub * 4;            // embed columns [col, col+3]

    float4 w[NRAD];
#pragma unroll
    for (int r = 0; r < NRAD; ++r)
        w[r] = *reinterpret_cast<const float4*>(&W_rbf[r * EMBED + col]);

    const int gpb = blockDim.x >> 5;    // edge groups per block (8)
    long long e = (long long)blockIdx.x * gpb + (threadIdx.x >> 5);
    const long long estep = (long long)gridDim.x * gpb;

    for (; e < n_edges; e += estep) {
        const float4* rr = reinterpret_cast<const float4*>(rbf + e * NRAD);
        float4 q0 = rr[0], q1 = rr[1], q2 = rr[2], q3 = rr[3];
        float rv[NRAD] = {q0.x, q0.y, q0.z, q0.w, q1.x, q1.y, q1.z, q1.w,
                          q2.x, q2.y, q2.z, q2.w, q3.x, q3.y, q3.z, q3.w};
        float tx = 0.f, ty = 0.f, tz = 0.f, tw = 0.f;
#pragma unroll
        for (int r = 0; r < NRAD; ++r) {
            tx = fmaf(rv[r], w[r].x, tx);
            ty = fmaf(rv[r], w[r].y, ty);
            tz = fmaf(rv[r], w[r].z, tz);
            tw = fmaf(rv[r], w[r].w, tw);
        }
        float4 m = *reinterpret_cast<const float4*>(messages + e * EMBED + col);
        float* dst = summed + (long long)idx_i[e] * EMBED + col;
        atomicAdd(dst + 0, m.x * tx);
        atomicAdd(dst + 1, m.y * ty);
        atomicAdd(dst + 2, m.z * tz);
        atomicAdd(dst + 3, m.w * tw);
    }
}

// ---------------------------------------------------------------------------
// Phase 2: fp32 GEMM  C[M,N] = A[M,K] @ B[K,N]  (+bias, +swish optional).
// 64x64 block tile, 256 threads, 4x4 thread tile, BK=16.
// A staged transposed in LDS so both fragments are ds_read_b128.
// ---------------------------------------------------------------------------
template <int K, bool BIAS, bool SWISH>
__global__ __launch_bounds__(256) void mlp_gemm_kernel(
    const float* __restrict__ A, const float* __restrict__ B,
    const float* __restrict__ bias, float* __restrict__ C, int M, int N)
{
    constexpr int BM = 64, BN = 64, BK = 16;
    __shared__ float Ast[BK][BM];   // transposed A tile
    __shared__ float Bs[BK][BN];

    const int tid = threadIdx.x;
    const int tx = tid & 15, ty = tid >> 4;
    const int row0 = blockIdx.x * BM, col0 = blockIdx.y * BN;

    const int arow  = tid >> 2;        // 0..63
    const int akcol = (tid & 3) * 4;   // 0,4,8,12
    const int brow  = tid >> 4;        // 0..15
    const int bcol  = (tid & 15) * 4;  // 0..60

    float acc[4][4] = {};

    for (int k0 = 0; k0 < K; k0 += BK) {
        float4 av = make_float4(0.f, 0.f, 0.f, 0.f);
        const int r = row0 + arow;
        if (r < M)
            av = *reinterpret_cast<const float4*>(&A[(long long)r * K + k0 + akcol]);
        const float4 bv =
            *reinterpret_cast<const float4*>(&B[(long long)(k0 + brow) * N + col0 + bcol]);

        __syncthreads();  // previous iteration's LDS reads complete
        Ast[akcol + 0][arow] = av.x;
        Ast[akcol + 1][arow] = av.y;
        Ast[akcol + 2][arow] = av.z;
        Ast[akcol + 3][arow] = av.w;
        *reinterpret_cast<float4*>(&Bs[brow][bcol]) = bv;
        __syncthreads();

#pragma unroll
        for (int kk = 0; kk < BK; ++kk) {
            const float4 a4 = *reinterpret_cast<const float4*>(&Ast[kk][ty * 4]);
            const float4 b4 = *reinterpret_cast<const float4*>(&Bs[kk][tx * 4]);
            const float a[4] = {a4.x, a4.y, a4.z, a4.w};
            const float b[4] = {b4.x, b4.y, b4.z, b4.w};
#pragma unroll
            for (int i = 0; i < 4; ++i)
#pragma unroll
                for (int j = 0; j < 4; ++j)
                    acc[i][j] = fmaf(a[i], b[j], acc[i][j]);
        }
    }

#pragma unroll
    for (int i = 0; i < 4; ++i) {
        const int r = row0 + ty * 4 + i;
        if (r >= M) continue;
        float vals[4];
#pragma unroll
        for (int j = 0; j < 4; ++j) {
            float v = acc[i][j];
            if (BIAS) v += bias[col0 + tx * 4 + j];
            if (SWISH) v = v / (1.0f + expf(-v));
            vals[j] = v;
        }
        *reinterpret_cast<float4*>(&C[(long long)r * N + col0 + tx * 4]) =
            make_float4(vals[0], vals[1], vals[2], vals[3]);
    }
}

// ---------------------------------------------------------------------------
// Phase 3: final [OUTE]->1 dot per row. One wave per row, shuffle reduce.
// ---------------------------------------------------------------------------
__global__ __launch_bounds__(256) void final_dot_kernel(
    const float* __restrict__ h, const float* __restrict__ Wf,
    float* __restrict__ out, int M)
{
    const int lane = threadIdx.x & 63;
    const int wv   = threadIdx.x >> 6;
    const int row  = blockIdx.x * 4 + wv;
    if (row >= M) return;

    const float* hr = h + (long long)row * OUTE;
    float s = 0.f;
#pragma unroll
    for (int j = 0; j < OUTE / 64; ++j)
        s = fmaf(hr[lane + j * 64], Wf[lane + j * 64], s);
#pragma unroll
    for (int off = 32; off > 0; off >>= 1)
        s += __shfl_down(s, off);
    if (lane == 0) out[row] = s;
}

extern "C" void kernel_launch(void* const* d_in, const int* in_sizes, int n_in,
                              void* d_out, int out_size, void* d_ws, size_t ws_size,
                              hipStream_t stream)
{
    const float* messages = (const float*)d_in[0];
    const float* rbf      = (const float*)d_in[1];
    const int*   idx_i    = (const int*)d_in[2];
    // d_in[3] = idx_j (unused by the reference output path)
    const float* W_rbf    = (const float*)d_in[4];
    const float* W_up     = (const float*)d_in[5];
    const float* W1       = (const float*)d_in[6];
    const float* b1       = (const float*)d_in[7];
    const float* W2       = (const float*)d_in[8];
    const float* b2       = (const float*)d_in[9];
    const float* W3       = (const float*)d_in[10];
    const float* b3       = (const float*)d_in[11];
    const float* Wf       = (const float*)d_in[12];
    float* out = (float*)d_out;

    const int n_edges = in_sizes[2];
    const int M = out_size;  // NUM_TARGETS == 1 -> out_size == N_PARTICLES

    char* ws = (char*)d_ws;
    float* summed = (float*)ws;                                         // M*128 f32
    float* hA = (float*)(ws + (size_t)M * EMBED * sizeof(float));       // M*256 f32
    float* hB = hA + (size_t)M * OUTE;                                  // M*256 f32

    hipMemsetAsync(summed, 0, (size_t)M * EMBED * sizeof(float), stream);

    edge_scatter_kernel<<<4096, 256, 0, stream>>>(messages, rbf, idx_i, W_rbf,
                                                  summed, n_edges);

    dim3 g1((M + 63) / 64, OUTE / 64);
    mlp_gemm_kernel<EMBED, false, false><<<g1, 256, 0, stream>>>(summed, W_up, nullptr, hA, M, OUTE);
    mlp_gemm_kernel<OUTE, true, true><<<g1, 256, 0, stream>>>(hA, W1, b1, hB, M, OUTE);
    mlp_gemm_kernel<OUTE, true, true><<<g1, 256, 0, stream>>>(hB, W2, b2, hA, M, OUTE);
    mlp_gemm_kernel<OUTE, true, true><<<g1, 256, 0, stream>>>(hA, W3, b3, hB, M, OUTE);

    final_dot_kernel<<<(M + 3) / 4, 256, 0, stream>>>(hB, Wf, out, M);
}

// Round 2
// 949.716 us; speedup vs baseline: 2.1785x; 2.1785x over previous
//
#include <hip/hip_runtime.h>
#include <hip/hip_bf16.h>

#define EMBED 128
#define NRAD  16
#define OUTE  256

// ---------------------------------------------------------------------------
// Phase 1a: histogram of receiving-atom indices.
// ---------------------------------------------------------------------------
__global__ __launch_bounds__(256) void hist_kernel(const int* __restrict__ idx_i,
                                                   int* __restrict__ counts, int n_edges)
{
    for (int e = blockIdx.x * blockDim.x + threadIdx.x; e < n_edges;
         e += gridDim.x * blockDim.x)
        atomicAdd(&counts[idx_i[e]], 1);
}

// ---------------------------------------------------------------------------
// Phase 1b: single-block exclusive scan of counts -> cursor (bucket starts).
// ---------------------------------------------------------------------------
__global__ __launch_bounds__(1024) void scan_kernel(const int* __restrict__ counts,
                                                    int* __restrict__ cursor, int n)
{
    __shared__ int partial[1024];
    const int tid = threadIdx.x;
    const int chunk = (n + 1023) / 1024;
    const int lo = min(tid * chunk, n), hi = min(lo + chunk, n);
    int s = 0;
    for (int i = lo; i < hi; ++i) s += counts[i];
    partial[tid] = s;
    __syncthreads();
    for (int off = 1; off < 1024; off <<= 1) {
        int v = (tid >= off) ? partial[tid - off] : 0;
        __syncthreads();
        partial[tid] += v;
        __syncthreads();
    }
    int run = (tid > 0) ? partial[tid - 1] : 0;  // exclusive prefix of this chunk
    for (int i = lo; i < hi; ++i) {
        cursor[i] = run;
        run += counts[i];
    }
}

// ---------------------------------------------------------------------------
// Phase 1c: scatter edge ids into CSR order. cursor[p] becomes bucket END.
// ---------------------------------------------------------------------------
__global__ __launch_bounds__(256) void scatter_ids_kernel(const int* __restrict__ idx_i,
                                                          int* __restrict__ cursor,
                                                          int* __restrict__ edge_order,
                                                          int n_edges)
{
    for (int e = blockIdx.x * blockDim.x + threadIdx.x; e < n_edges;
         e += gridDim.x * blockDim.x) {
        const int pos = atomicAdd(&cursor[idx_i[e]], 1);
        edge_order[pos] = e;
    }
}

// ---------------------------------------------------------------------------
// Phase 1d: per-particle gather-reduce. One wave per particle; lane owns 2
// embed columns. W_rbf slice kept in registers across grid-stride loop.
// summed row written exactly once (no atomics, no pre-memset needed).
// ---------------------------------------------------------------------------
__global__ __launch_bounds__(256) void gather_reduce_kernel(
    const float* __restrict__ messages, const float* __restrict__ rbf,
    const int* __restrict__ edge_order, const int* __restrict__ counts,
    const int* __restrict__ cursor_end, const float* __restrict__ W_rbf,
    float* __restrict__ summed, int n_particles)
{
    const int lane = threadIdx.x & 63;
    const int col = lane * 2;

    float2 w[NRAD];
#pragma unroll
    for (int r = 0; r < NRAD; ++r)
        w[r] = *reinterpret_cast<const float2*>(&W_rbf[r * EMBED + col]);

    const int wpb = blockDim.x >> 6;  // waves per block (4)
    int p = blockIdx.x * wpb + (threadIdx.x >> 6);
    const int pstep = gridDim.x * wpb;

    for (; p < n_particles; p += pstep) {
        const int end = cursor_end[p];
        const int start = end - counts[p];
        float ax = 0.f, ay = 0.f;
        for (int ei = start; ei < end; ++ei) {
            const int e = edge_order[ei];
            const float4* rr = reinterpret_cast<const float4*>(rbf + (long long)e * NRAD);
            const float4 q0 = rr[0], q1 = rr[1], q2 = rr[2], q3 = rr[3];
            const float rv[NRAD] = {q0.x, q0.y, q0.z, q0.w, q1.x, q1.y, q1.z, q1.w,
                                    q2.x, q2.y, q2.z, q2.w, q3.x, q3.y, q3.z, q3.w};
            float tx = 0.f, ty = 0.f;
#pragma unroll
            for (int r = 0; r < NRAD; ++r) {
                tx = fmaf(rv[r], w[r].x, tx);
                ty = fmaf(rv[r], w[r].y, ty);
            }
            const float2 m =
                *reinterpret_cast<const float2*>(messages + (long long)e * EMBED + col);
            ax = fmaf(m.x, tx, ax);
            ay = fmaf(m.y, ty, ay);
        }
        *reinterpret_cast<float2*>(&summed[(long long)p * EMBED + col]) =
            make_float2(ax, ay);
    }
}

// ---------------------------------------------------------------------------
// Phase 2: fp32 GEMM  C[M,N] = A[M,K] @ B[K,N]  (+bias, +swish optional).
// 64x64 block tile, 256 threads, 4x4 thread tile, BK=16. (unchanged from R0)
// ---------------------------------------------------------------------------
template <int K, bool BIAS, bool SWISH>
__global__ __launch_bounds__(256) void mlp_gemm_kernel(
    const float* __restrict__ A, const float* __restrict__ B,
    const float* __restrict__ bias, float* __restrict__ C, int M, int N)
{
    constexpr int BM = 64, BN = 64, BK = 16;
    __shared__ float Ast[BK][BM];
    __shared__ float Bs[BK][BN];

    const int tid = threadIdx.x;
    const int tx = tid & 15, ty = tid >> 4;
    const int row0 = blockIdx.x * BM, col0 = blockIdx.y * BN;

    const int arow  = tid >> 2;
    const int akcol = (tid & 3) * 4;
    const int brow  = tid >> 4;
    const int bcol  = (tid & 15) * 4;

    float acc[4][4] = {};

    for (int k0 = 0; k0 < K; k0 += BK) {
        float4 av = make_float4(0.f, 0.f, 0.f, 0.f);
        const int r = row0 + arow;
        if (r < M)
            av = *reinterpret_cast<const float4*>(&A[(long long)r * K + k0 + akcol]);
        const float4 bv =
            *reinterpret_cast<const float4*>(&B[(long long)(k0 + brow) * N + col0 + bcol]);

        __syncthreads();
        Ast[akcol + 0][arow] = av.x;
        Ast[akcol + 1][arow] = av.y;
        Ast[akcol + 2][arow] = av.z;
        Ast[akcol + 3][arow] = av.w;
        *reinterpret_cast<float4*>(&Bs[brow][bcol]) = bv;
        __syncthreads();

#pragma unroll
        for (int kk = 0; kk < BK; ++kk) {
            const float4 a4 = *reinterpret_cast<const float4*>(&Ast[kk][ty * 4]);
            const float4 b4 = *reinterpret_cast<const float4*>(&Bs[kk][tx * 4]);
            const float a[4] = {a4.x, a4.y, a4.z, a4.w};
            const float b[4] = {b4.x, b4.y, b4.z, b4.w};
#pragma unroll
            for (int i = 0; i < 4; ++i)
#pragma unroll
                for (int j = 0; j < 4; ++j)
                    acc[i][j] = fmaf(a[i], b[j], acc[i][j]);
        }
    }

#pragma unroll
    for (int i = 0; i < 4; ++i) {
        const int r = row0 + ty * 4 + i;
        if (r >= M) continue;
        float vals[4];
#pragma unroll
        for (int j = 0; j < 4; ++j) {
            float v = acc[i][j];
            if (BIAS) v += bias[col0 + tx * 4 + j];
            if (SWISH) v = v / (1.0f + expf(-v));
            vals[j] = v;
        }
        *reinterpret_cast<float4*>(&C[(long long)r * N + col0 + tx * 4]) =
            make_float4(vals[0], vals[1], vals[2], vals[3]);
    }
}

// ---------------------------------------------------------------------------
// Phase 3: final [OUTE]->1 dot per row. One wave per row, shuffle reduce.
// ---------------------------------------------------------------------------
__global__ __launch_bounds__(256) void final_dot_kernel(
    const float* __restrict__ h, const float* __restrict__ Wf,
    float* __restrict__ out, int M)
{
    const int lane = threadIdx.x & 63;
    const int wv   = threadIdx.x >> 6;
    const int row  = blockIdx.x * 4 + wv;
    if (row >= M) return;

    const float* hr = h + (long long)row * OUTE;
    float s = 0.f;
#pragma unroll
    for (int j = 0; j < OUTE / 64; ++j)
        s = fmaf(hr[lane + j * 64], Wf[lane + j * 64], s);
#pragma unroll
    for (int off = 32; off > 0; off >>= 1)
        s += __shfl_down(s, off);
    if (lane == 0) out[row] = s;
}

extern "C" void kernel_launch(void* const* d_in, const int* in_sizes, int n_in,
                              void* d_out, int out_size, void* d_ws, size_t ws_size,
                              hipStream_t stream)
{
    const float* messages = (const float*)d_in[0];
    const float* rbf      = (const float*)d_in[1];
    const int*   idx_i    = (const int*)d_in[2];
    // d_in[3] = idx_j (unused by the reference output path)
    const float* W_rbf    = (const float*)d_in[4];
    const float* W_up     = (const float*)d_in[5];
    const float* W1       = (const float*)d_in[6];
    const float* b1       = (const float*)d_in[7];
    const float* W2       = (const float*)d_in[8];
    const float* b2       = (const float*)d_in[9];
    const float* W3       = (const float*)d_in[10];
    const float* b3       = (const float*)d_in[11];
    const float* Wf       = (const float*)d_in[12];
    float* out = (float*)d_out;

    const int n_edges = in_sizes[2];
    const int M = out_size;  // NUM_TARGETS == 1 -> out_size == N_PARTICLES

    char* ws = (char*)d_ws;
    float* summed = (float*)ws;                                      // M*128 f32
    float* hA = (float*)(ws + (size_t)M * EMBED * sizeof(float));    // M*256 f32
    float* hB = hA + (size_t)M * OUTE;                               // M*256 f32

    // CSR scratch aliases the hA region (dead until GEMM-1, fully rewritten
    // every call -> safe across graph replays).
    int* counts     = (int*)hA;           // M ints
    int* cursor     = counts + M;         // M ints (starts, then ends)
    int* edge_order = cursor + M;         // n_edges ints

    hipMemsetAsync(counts, 0, (size_t)M * sizeof(int), stream);
    hist_kernel<<<4096, 256, 0, stream>>>(idx_i, counts, n_edges);
    scan_kernel<<<1, 1024, 0, stream>>>(counts, cursor, M);
    scatter_ids_kernel<<<4096, 256, 0, stream>>>(idx_i, cursor, edge_order, n_edges);
    gather_reduce_kernel<<<2048, 256, 0, stream>>>(messages, rbf, edge_order, counts,
                                                   cursor, W_rbf, summed, M);

    dim3 g1((M + 63) / 64, OUTE / 64);
    mlp_gemm_kernel<EMBED, false, false><<<g1, 256, 0, stream>>>(summed, W_up, nullptr, hA, M, OUTE);
    mlp_gemm_kernel<OUTE, true, true><<<g1, 256, 0, stream>>>(hA, W1, b1, hB, M, OUTE);
    mlp_gemm_kernel<OUTE, true, true><<<g1, 256, 0, stream>>>(hB, W2, b2, hA, M, OUTE);
    mlp_gemm_kernel<OUTE, true, true><<<g1, 256, 0, stream>>>(hA, W3, b3, hB, M, OUTE);

    final_dot_kernel<<<(M + 3) / 4, 256, 0, stream>>>(hB, Wf, out, M);
}

// Round 3
// 570.970 us; speedup vs baseline: 3.6236x; 1.6633x over previous
//
#include <hip/hip_runtime.h>
#include <hip/hip_bf16.h>

#define EMBED 128
#define NRAD  16
#define OUTE  256

typedef __bf16 bf16x8 __attribute__((ext_vector_type(8)));
typedef float  f32x4  __attribute__((ext_vector_type(4)));

static __device__ __forceinline__ unsigned short f2bf(float x) {
    return __builtin_bit_cast(unsigned short, (__bf16)x);
}

// ---------------------------------------------------------------------------
// Phase 1a: histogram of receiving-atom indices.
// ---------------------------------------------------------------------------
__global__ __launch_bounds__(256) void hist_kernel(const int* __restrict__ idx_i,
                                                   int* __restrict__ counts, int n_edges)
{
    for (int e = blockIdx.x * blockDim.x + threadIdx.x; e < n_edges;
         e += gridDim.x * blockDim.x)
        atomicAdd(&counts[idx_i[e]], 1);
}

// ---------------------------------------------------------------------------
// Phase 1b: single-block exclusive scan of counts -> cursor (bucket starts).
// ---------------------------------------------------------------------------
__global__ __launch_bounds__(1024) void scan_kernel(const int* __restrict__ counts,
                                                    int* __restrict__ cursor, int n)
{
    __shared__ int partial[1024];
    const int tid = threadIdx.x;
    const int chunk = (n + 1023) / 1024;
    const int lo = min(tid * chunk, n), hi = min(lo + chunk, n);
    int s = 0;
    for (int i = lo; i < hi; ++i) s += counts[i];
    partial[tid] = s;
    __syncthreads();
    for (int off = 1; off < 1024; off <<= 1) {
        int v = (tid >= off) ? partial[tid - off] : 0;
        __syncthreads();
        partial[tid] += v;
        __syncthreads();
    }
    int run = (tid > 0) ? partial[tid - 1] : 0;
    for (int i = lo; i < hi; ++i) {
        cursor[i] = run;
        run += counts[i];
    }
}

// ---------------------------------------------------------------------------
// Phase 1c: scatter edge ids into CSR order. cursor[p] becomes bucket END.
// ---------------------------------------------------------------------------
__global__ __launch_bounds__(256) void scatter_ids_kernel(const int* __restrict__ idx_i,
                                                          int* __restrict__ cursor,
                                                          int* __restrict__ edge_order,
                                                          int n_edges)
{
    for (int e = blockIdx.x * blockDim.x + threadIdx.x; e < n_edges;
         e += gridDim.x * blockDim.x) {
        const int pos = atomicAdd(&cursor[idx_i[e]], 1);
        edge_order[pos] = e;
    }
}

// ---------------------------------------------------------------------------
// Phase 1d: per-particle gather-reduce, 4-edge unrolled for MLP.
// ---------------------------------------------------------------------------
__device__ __forceinline__ float2 rbf_dot(float4 q0, float4 q1, float4 q2, float4 q3,
                                          const float2* w)
{
    const float rv[NRAD] = {q0.x, q0.y, q0.z, q0.w, q1.x, q1.y, q1.z, q1.w,
                            q2.x, q2.y, q2.z, q2.w, q3.x, q3.y, q3.z, q3.w};
    float tx = 0.f, ty = 0.f;
#pragma unroll
    for (int r = 0; r < NRAD; ++r) {
        tx = fmaf(rv[r], w[r].x, tx);
        ty = fmaf(rv[r], w[r].y, ty);
    }
    return make_float2(tx, ty);
}

__global__ __launch_bounds__(256, 4) void gather_reduce_kernel(
    const float* __restrict__ messages, const float* __restrict__ rbf,
    const int* __restrict__ edge_order, const int* __restrict__ counts,
    const int* __restrict__ cursor_end, const float* __restrict__ W_rbf,
    float* __restrict__ summed, int n_particles)
{
    const int lane = threadIdx.x & 63;
    const int col = lane * 2;

    float2 w[NRAD];
#pragma unroll
    for (int r = 0; r < NRAD; ++r)
        w[r] = *reinterpret_cast<const float2*>(&W_rbf[r * EMBED + col]);

    int p = blockIdx.x * 4 + (threadIdx.x >> 6);
    const int pstep = gridDim.x * 4;

    for (; p < n_particles; p += pstep) {
        const int end = cursor_end[p];
        const int start = end - counts[p];
        float ax = 0.f, ay = 0.f;
        int ei = start;
        // 4-edge unroll: all loads issued before FMAs -> 4 independent chains
        for (; ei + 4 <= end; ei += 4) {
            const int e0 = edge_order[ei + 0];
            const int e1 = edge_order[ei + 1];
            const int e2 = edge_order[ei + 2];
            const int e3 = edge_order[ei + 3];
            const float4* R0 = reinterpret_cast<const float4*>(rbf + (long long)e0 * NRAD);
            const float4* R1 = reinterpret_cast<const float4*>(rbf + (long long)e1 * NRAD);
            const float4* R2 = reinterpret_cast<const float4*>(rbf + (long long)e2 * NRAD);
            const float4* R3 = reinterpret_cast<const float4*>(rbf + (long long)e3 * NRAD);
            const float4 a0 = R0[0], a1 = R0[1], a2 = R0[2], a3 = R0[3];
            const float4 b0 = R1[0], b1 = R1[1], b2 = R1[2], b3 = R1[3];
            const float4 c0 = R2[0], c1 = R2[1], c2 = R2[2], c3 = R2[3];
            const float4 d0 = R3[0], d1 = R3[1], d2 = R3[2], d3 = R3[3];
            const float2 m0 = *reinterpret_cast<const float2*>(messages + (long long)e0 * EMBED + col);
            const float2 m1 = *reinterpret_cast<const float2*>(messages + (long long)e1 * EMBED + col);
            const float2 m2 = *reinterpret_cast<const float2*>(messages + (long long)e2 * EMBED + col);
            const float2 m3 = *reinterpret_cast<const float2*>(messages + (long long)e3 * EMBED + col);
            const float2 t0 = rbf_dot(a0, a1, a2, a3, w);
            const float2 t1 = rbf_dot(b0, b1, b2, b3, w);
            const float2 t2 = rbf_dot(c0, c1, c2, c3, w);
            const float2 t3 = rbf_dot(d0, d1, d2, d3, w);
            ax = fmaf(m0.x, t0.x, ax); ay = fmaf(m0.y, t0.y, ay);
            ax = fmaf(m1.x, t1.x, ax); ay = fmaf(m1.y, t1.y, ay);
            ax = fmaf(m2.x, t2.x, ax); ay = fmaf(m2.y, t2.y, ay);
            ax = fmaf(m3.x, t3.x, ax); ay = fmaf(m3.y, t3.y, ay);
        }
        for (; ei < end; ++ei) {
            const int e = edge_order[ei];
            const float4* R = reinterpret_cast<const float4*>(rbf + (long long)e * NRAD);
            const float2 t = rbf_dot(R[0], R[1], R[2], R[3], w);
            const float2 m = *reinterpret_cast<const float2*>(messages + (long long)e * EMBED + col);
            ax = fmaf(m.x, t.x, ax);
            ay = fmaf(m.y, t.y, ay);
        }
        *reinterpret_cast<float2*>(&summed[(long long)p * EMBED + col]) =
            make_float2(ax, ay);
    }
}

// ---------------------------------------------------------------------------
// Weight prep: cast + transpose to bf16 W^T [N][K] so MFMA B-frags are
// contiguous-k b128 loads. Rewritten every call (graph-replay safe).
// ---------------------------------------------------------------------------
__global__ __launch_bounds__(256) void prep_weights_kernel(
    const float* __restrict__ Wup, const float* __restrict__ W1,
    const float* __restrict__ W2, const float* __restrict__ W3,
    __bf16* __restrict__ WupT, __bf16* __restrict__ W1T,
    __bf16* __restrict__ W2T, __bf16* __restrict__ W3T)
{
    const int total = OUTE * EMBED + 3 * OUTE * OUTE;
    for (int id = blockIdx.x * blockDim.x + threadIdx.x; id < total;
         id += gridDim.x * blockDim.x) {
        if (id < OUTE * EMBED) {
            const int n = id / EMBED, k = id % EMBED;
            WupT[id] = (__bf16)Wup[k * OUTE + n];
        } else {
            const int r = id - OUTE * EMBED;
            const int wsel = r / (OUTE * OUTE);
            const int rr = r % (OUTE * OUTE);
            const int n = rr / OUTE, k = rr % OUTE;
            const float* src = (wsel == 0) ? W1 : ((wsel == 1) ? W2 : W3);
            __bf16* dst = (wsel == 0) ? W1T : ((wsel == 1) ? W2T : W3T);
            dst[rr] = (__bf16)src[k * OUTE + n];
        }
    }
}

// ---------------------------------------------------------------------------
// Phase 2+3 fused: whole MLP for a 64-row tile, bf16 MFMA, h in LDS only.
// LDS layout: [64 rows][256 cols] bf16, byte ^= ((row&7)<<4) XOR swizzle
// (G4: 16 lanes reading 16 rows @ stride 512B would be 16-way conflicted).
// MFMA 16x16x32 bf16 layouts (m89/m92): A row=lane&15, k=(lane>>4)*8+j;
// B col=lane&15, same k; C/D col=lane&15, row=(lane>>4)*4+reg.
// ---------------------------------------------------------------------------
template <int K, bool ACT>
__device__ __forceinline__ void mlp_layer(const unsigned short* lin, unsigned short* lout,
                                          const __bf16* __restrict__ Wt,
                                          const float* __restrict__ bias, int l, int w)
{
    f32x4 acc[4][4];
#pragma unroll
    for (int i = 0; i < 4; ++i)
#pragma unroll
        for (int j = 0; j < 4; ++j)
            acc[i][j] = (f32x4){0.f, 0.f, 0.f, 0.f};

    const int lr = l & 15;
    const int hi = l >> 4;
    const int kg = hi * 8;

#pragma unroll
    for (int kk = 0; kk < K; kk += 32) {
        bf16x8 af[4], bf_[4];
#pragma unroll
        for (int i = 0; i < 4; ++i) {
            const int row = i * 16 + lr;
            const int byte = row * 512 + (((kk + kg) * 2) ^ ((row & 7) << 4));
            af[i] = *reinterpret_cast<const bf16x8*>(
                reinterpret_cast<const char*>(lin) + byte);
        }
#pragma unroll
        for (int j = 0; j < 4; ++j) {
            const int n = w * 64 + j * 16 + lr;
            bf_[j] = *reinterpret_cast<const bf16x8*>(Wt + (size_t)n * K + kk + kg);
        }
#pragma unroll
        for (int i = 0; i < 4; ++i)
#pragma unroll
            for (int j = 0; j < 4; ++j)
                acc[i][j] = __builtin_amdgcn_mfma_f32_16x16x32_bf16(af[i], bf_[j],
                                                                    acc[i][j], 0, 0, 0);
    }

    float bb[4];
#pragma unroll
    for (int j = 0; j < 4; ++j)
        bb[j] = ACT ? bias[w * 64 + j * 16 + lr] : 0.f;

#pragma unroll
    for (int j = 0; j < 4; ++j) {
        const int colb = (w * 64 + j * 16 + lr) * 2;
#pragma unroll
        for (int i = 0; i < 4; ++i) {
#pragma unroll
            for (int r = 0; r < 4; ++r) {
                const int row = i * 16 + hi * 4 + r;
                float v = acc[i][j][r];
                if (ACT) {
                    v += bb[j];
                    v = v / (1.f + __expf(-v));
                }
                const int byte = row * 512 + (colb ^ ((row & 7) << 4));
                *reinterpret_cast<unsigned short*>(
                    reinterpret_cast<char*>(lout) + byte) = f2bf(v);
            }
        }
    }
}

__global__ __launch_bounds__(256) void fused_mlp_kernel(
    const float* __restrict__ summed,
    const __bf16* __restrict__ WupT, const __bf16* __restrict__ W1T,
    const __bf16* __restrict__ W2T, const __bf16* __restrict__ W3T,
    const float* __restrict__ b1, const float* __restrict__ b2,
    const float* __restrict__ b3, const float* __restrict__ Wf,
    float* __restrict__ out, int M)
{
    __shared__ __align__(16) unsigned short buf0[64 * 256];
    __shared__ __align__(16) unsigned short buf1[64 * 256];

    const int tid = threadIdx.x;
    const int l = tid & 63, w = tid >> 6;
    const int row0 = blockIdx.x * 64;

    // stage summed rows -> buf0 (bf16, swizzled), cols 0..127
#pragma unroll
    for (int i = 0; i < 8; ++i) {
        const int id = tid + i * 256;       // 0..2047: 64 rows x 32 float4
        const int row = id >> 5;
        const int c = (id & 31) * 4;
        float4 v = make_float4(0.f, 0.f, 0.f, 0.f);
        const int gr = row0 + row;
        if (gr < M)
            v = *reinterpret_cast<const float4*>(summed + (long long)gr * EMBED + c);
        ushort4 u = make_ushort4(f2bf(v.x), f2bf(v.y), f2bf(v.z), f2bf(v.w));
        const int byte = row * 512 + ((c * 2) ^ ((row & 7) << 4));
        *reinterpret_cast<ushort4*>(reinterpret_cast<char*>(buf0) + byte) = u;
    }
    __syncthreads();

    mlp_layer<EMBED, false>(buf0, buf1, WupT, nullptr, l, w);
    __syncthreads();
    mlp_layer<OUTE, true>(buf1, buf0, W1T, b1, l, w);
    __syncthreads();
    mlp_layer<OUTE, true>(buf0, buf1, W2T, b2, l, w);
    __syncthreads();
    mlp_layer<OUTE, true>(buf1, buf0, W3T, b3, l, w);
    __syncthreads();

    // final dot: h[row,:] . Wf  (4 threads per row, 64 k each)
    const int row = tid >> 2, q = tid & 3;
    float s = 0.f;
#pragma unroll
    for (int c = 0; c < 8; ++c) {
        const int k = q * 64 + c * 8;
        const int byte = row * 512 + ((k * 2) ^ ((row & 7) << 4));
        const bf16x8 hv = *reinterpret_cast<const bf16x8*>(
            reinterpret_cast<const char*>(buf0) + byte);
        const float4 wa = *reinterpret_cast<const float4*>(Wf + k);
        const float4 wb = *reinterpret_cast<const float4*>(Wf + k + 4);
        s += (float)hv[0] * wa.x + (float)hv[1] * wa.y +
             (float)hv[2] * wa.z + (float)hv[3] * wa.w +
             (float)hv[4] * wb.x + (float)hv[5] * wb.y +
             (float)hv[6] * wb.z + (float)hv[7] * wb.w;
    }
    s += __shfl_xor(s, 1);
    s += __shfl_xor(s, 2);
    if (q == 0 && row0 + row < M) out[row0 + row] = s;
}

extern "C" void kernel_launch(void* const* d_in, const int* in_sizes, int n_in,
                              void* d_out, int out_size, void* d_ws, size_t ws_size,
                              hipStream_t stream)
{
    const float* messages = (const float*)d_in[0];
    const float* rbf      = (const float*)d_in[1];
    const int*   idx_i    = (const int*)d_in[2];
    // d_in[3] = idx_j (unused)
    const float* W_rbf    = (const float*)d_in[4];
    const float* W_up     = (const float*)d_in[5];
    const float* W1       = (const float*)d_in[6];
    const float* b1       = (const float*)d_in[7];
    const float* W2       = (const float*)d_in[8];
    const float* b2       = (const float*)d_in[9];
    const float* W3       = (const float*)d_in[10];
    const float* b3       = (const float*)d_in[11];
    const float* Wf       = (const float*)d_in[12];
    float* out = (float*)d_out;

    const int n_edges = in_sizes[2];
    const int M = out_size;  // NUM_TARGETS == 1 -> out_size == N_PARTICLES

    char* ws = (char*)d_ws;
    size_t off = 0;
    float* summed = (float*)(ws + off); off += (size_t)M * EMBED * sizeof(float);
    int* counts     = (int*)(ws + off); off += (size_t)M * sizeof(int);
    int* cursor     = (int*)(ws + off); off += (size_t)M * sizeof(int);
    int* edge_order = (int*)(ws + off); off += (size_t)n_edges * sizeof(int);
    off = (off + 255) & ~(size_t)255;
    __bf16* WupT = (__bf16*)(ws + off); off += (size_t)OUTE * EMBED * 2;
    __bf16* W1T  = (__bf16*)(ws + off); off += (size_t)OUTE * OUTE * 2;
    __bf16* W2T  = (__bf16*)(ws + off); off += (size_t)OUTE * OUTE * 2;
    __bf16* W3T  = (__bf16*)(ws + off); off += (size_t)OUTE * OUTE * 2;

    hipMemsetAsync(counts, 0, (size_t)M * sizeof(int), stream);
    hist_kernel<<<4096, 256, 0, stream>>>(idx_i, counts, n_edges);
    scan_kernel<<<1, 1024, 0, stream>>>(counts, cursor, M);
    scatter_ids_kernel<<<4096, 256, 0, stream>>>(idx_i, cursor, edge_order, n_edges);
    prep_weights_kernel<<<896, 256, 0, stream>>>(W_up, W1, W2, W3, WupT, W1T, W2T, W3T);
    gather_reduce_kernel<<<2048, 256, 0, stream>>>(messages, rbf, edge_order, counts,
                                                   cursor, W_rbf, summed, M);
    fused_mlp_kernel<<<(M + 63) / 64, 256, 0, stream>>>(summed, WupT, W1T, W2T, W3T,
                                                        b1, b2, b3, Wf, out, M);
}

// Round 4
// 440.955 us; speedup vs baseline: 4.6921x; 1.2948x over previous
//
#include <hip/hip_runtime.h>
#include <hip/hip_bf16.h>

#define EMBED 128
#define NRAD  16
#define OUTE  256

typedef __bf16 bf16x8 __attribute__((ext_vector_type(8)));
typedef float  f32x4  __attribute__((ext_vector_type(4)));

static __device__ __forceinline__ unsigned short f2bf(float x) {
    return __builtin_bit_cast(unsigned short, (__bf16)x);
}

// ---------------------------------------------------------------------------
// Phase 1a: histogram of receiving-atom indices.
// ---------------------------------------------------------------------------
__global__ __launch_bounds__(256) void hist_kernel(const int* __restrict__ idx_i,
                                                   int* __restrict__ counts, int n_edges)
{
    for (int e = blockIdx.x * blockDim.x + threadIdx.x; e < n_edges;
         e += gridDim.x * blockDim.x)
        atomicAdd(&counts[idx_i[e]], 1);
}

// ---------------------------------------------------------------------------
// Phase 1b: single-block exclusive scan of counts -> cursor (bucket starts).
// ---------------------------------------------------------------------------
__global__ __launch_bounds__(1024) void scan_kernel(const int* __restrict__ counts,
                                                    int* __restrict__ cursor, int n)
{
    __shared__ int partial[1024];
    const int tid = threadIdx.x;
    const int chunk = (n + 1023) / 1024;
    const int lo = min(tid * chunk, n), hi = min(lo + chunk, n);
    int s = 0;
    for (int i = lo; i < hi; ++i) s += counts[i];
    partial[tid] = s;
    __syncthreads();
    for (int off = 1; off < 1024; off <<= 1) {
        int v = (tid >= off) ? partial[tid - off] : 0;
        __syncthreads();
        partial[tid] += v;
        __syncthreads();
    }
    int run = (tid > 0) ? partial[tid - 1] : 0;
    for (int i = lo; i < hi; ++i) {
        cursor[i] = run;
        run += counts[i];
    }
}

// ---------------------------------------------------------------------------
// Phase 1c: scatter edge ids into CSR order. cursor[p] becomes bucket END.
// ---------------------------------------------------------------------------
__global__ __launch_bounds__(256) void scatter_ids_kernel(const int* __restrict__ idx_i,
                                                          int* __restrict__ cursor,
                                                          int* __restrict__ edge_order,
                                                          int n_edges)
{
    for (int e = blockIdx.x * blockDim.x + threadIdx.x; e < n_edges;
         e += gridDim.x * blockDim.x) {
        const int pos = atomicAdd(&cursor[idx_i[e]], 1);
        edge_order[pos] = e;
    }
}

// ---------------------------------------------------------------------------
// Phase 1d: per-particle gather-reduce, software-pipelined.
// - One coalesced load fetches the particle's edge ids into the wave's lanes;
//   ids are then broadcast via __shfl (no id->data memory dependence).
// - rbf rows for the 64-edge window staged into wave-private LDS (coalesced,
//   no barriers); consume reads are wave-uniform float4 broadcasts.
// - messages double-buffered in registers: group g+1 issued before group g's
//   FMAs -> random 512B HBM reads stay in flight under compute.
// ---------------------------------------------------------------------------
__global__ __launch_bounds__(256, 4) void gather_reduce_kernel(
    const float* __restrict__ messages, const float* __restrict__ rbf,
    const int* __restrict__ edge_order, const int* __restrict__ counts,
    const int* __restrict__ cursor_end, const float* __restrict__ W_rbf,
    float* __restrict__ summed, int n_particles)
{
    __shared__ float rbf_s[4][64 * NRAD];   // 4 KB per wave, wave-private

    const int tid  = threadIdx.x;
    const int lane = tid & 63;
    const int wv   = tid >> 6;
    const int col  = lane * 2;
    float* lds = rbf_s[wv];

    float2 w[NRAD];
#pragma unroll
    for (int r = 0; r < NRAD; ++r)
        w[r] = *reinterpret_cast<const float2*>(&W_rbf[r * EMBED + col]);

    int p = blockIdx.x * 4 + wv;
    const int pstep = gridDim.x * 4;

    for (; p < n_particles; p += pstep) {
        const int end   = cursor_end[p];
        const int start = end - counts[p];
        float ax = 0.f, ay = 0.f;

        for (int w0 = start; w0 < end; w0 += 64) {
            const int n = min(end - w0, 64);                    // wave-uniform
            const int myid = edge_order[min(w0 + lane, end - 1)];

            // ---- stage rbf rows of this window into LDS (wave-private) ----
            const int subq = lane >> 4;      // edge-in-group-of-4
            const int rr   = lane & 15;      // radial index
            const int ng   = (n + 3) >> 2;   // groups of 4 edges
            for (int g = 0; g < ng; ++g) {
                const int ei = g * 4 + subq;
                const int eq = __shfl(myid, min(ei, n - 1), 64);
                lds[ei * NRAD + rr] = rbf[(long long)eq * NRAD + rr];
            }

            // ---- message double-buffer over 4-edge groups ----
            float2 mA[4], mB[4];
#pragma unroll
            for (int j = 0; j < 4; ++j) {
                const int e = __shfl(myid, min(j, n - 1), 64);
                mA[j] = *reinterpret_cast<const float2*>(
                    messages + (long long)e * EMBED + col);
                mB[j] = mA[j];
            }

            for (int i = 0; i < n; i += 4) {
                if (i + 4 < n) {            // issue next group (uniform branch)
#pragma unroll
                    for (int j = 0; j < 4; ++j) {
                        const int e = __shfl(myid, min(i + 4 + j, n - 1), 64);
                        mB[j] = *reinterpret_cast<const float2*>(
                            messages + (long long)e * EMBED + col);
                    }
                }
#pragma unroll
                for (int j = 0; j < 4; ++j) {
                    const float* lr = &lds[(i + j) * NRAD];
                    const float4 q0 = *reinterpret_cast<const float4*>(lr + 0);
                    const float4 q1 = *reinterpret_cast<const float4*>(lr + 4);
                    const float4 q2 = *reinterpret_cast<const float4*>(lr + 8);
                    const float4 q3 = *reinterpret_cast<const float4*>(lr + 12);
                    const float rv[NRAD] = {q0.x, q0.y, q0.z, q0.w,
                                            q1.x, q1.y, q1.z, q1.w,
                                            q2.x, q2.y, q2.z, q2.w,
                                            q3.x, q3.y, q3.z, q3.w};
                    float tx = 0.f, ty = 0.f;
#pragma unroll
                    for (int r = 0; r < NRAD; ++r) {
                        tx = fmaf(rv[r], w[r].x, tx);
                        ty = fmaf(rv[r], w[r].y, ty);
                    }
                    const float mk = (i + j < n) ? 1.f : 0.f;
                    ax = fmaf(mA[j].x * mk, tx, ax);
                    ay = fmaf(mA[j].y * mk, ty, ay);
                }
#pragma unroll
                for (int j = 0; j < 4; ++j) mA[j] = mB[j];
            }
        }
        *reinterpret_cast<float2*>(&summed[(long long)p * EMBED + col]) =
            make_float2(ax, ay);
    }
}

// ---------------------------------------------------------------------------
// Weight prep: cast + transpose to bf16 W^T [N][K].
// ---------------------------------------------------------------------------
__global__ __launch_bounds__(256) void prep_weights_kernel(
    const float* __restrict__ Wup, const float* __restrict__ W1,
    const float* __restrict__ W2, const float* __restrict__ W3,
    __bf16* __restrict__ WupT, __bf16* __restrict__ W1T,
    __bf16* __restrict__ W2T, __bf16* __restrict__ W3T)
{
    const int total = OUTE * EMBED + 3 * OUTE * OUTE;
    for (int id = blockIdx.x * blockDim.x + threadIdx.x; id < total;
         id += gridDim.x * blockDim.x) {
        if (id < OUTE * EMBED) {
            const int n = id / EMBED, k = id % EMBED;
            WupT[id] = (__bf16)Wup[k * OUTE + n];
        } else {
            const int r = id - OUTE * EMBED;
            const int wsel = r / (OUTE * OUTE);
            const int rr = r % (OUTE * OUTE);
            const int n = rr / OUTE, k = rr % OUTE;
            const float* src = (wsel == 0) ? W1 : ((wsel == 1) ? W2 : W3);
            __bf16* dst = (wsel == 0) ? W1T : ((wsel == 1) ? W2T : W3T);
            dst[rr] = (__bf16)src[k * OUTE + n];
        }
    }
}

// ---------------------------------------------------------------------------
// Phase 2+3 fused: whole MLP for a 64-row tile, bf16 MFMA, h in LDS only.
// LDS: [64][256] bf16, byte ^= ((row&7)<<4) XOR swizzle (G4).
// ---------------------------------------------------------------------------
template <int K, bool ACT>
__device__ __forceinline__ void mlp_layer(const unsigned short* lin, unsigned short* lout,
                                          const __bf16* __restrict__ Wt,
                                          const float* __restrict__ bias, int l, int w)
{
    f32x4 acc[4][4];
#pragma unroll
    for (int i = 0; i < 4; ++i)
#pragma unroll
        for (int j = 0; j < 4; ++j)
            acc[i][j] = (f32x4){0.f, 0.f, 0.f, 0.f};

    const int lr = l & 15;
    const int hi = l >> 4;
    const int kg = hi * 8;

#pragma unroll
    for (int kk = 0; kk < K; kk += 32) {
        bf16x8 af[4], bf_[4];
#pragma unroll
        for (int i = 0; i < 4; ++i) {
            const int row = i * 16 + lr;
            const int byte = row * 512 + (((kk + kg) * 2) ^ ((row & 7) << 4));
            af[i] = *reinterpret_cast<const bf16x8*>(
                reinterpret_cast<const char*>(lin) + byte);
        }
#pragma unroll
        for (int j = 0; j < 4; ++j) {
            const int n = w * 64 + j * 16 + lr;
            bf_[j] = *reinterpret_cast<const bf16x8*>(Wt + (size_t)n * K + kk + kg);
        }
#pragma unroll
        for (int i = 0; i < 4; ++i)
#pragma unroll
            for (int j = 0; j < 4; ++j)
                acc[i][j] = __builtin_amdgcn_mfma_f32_16x16x32_bf16(af[i], bf_[j],
                                                                    acc[i][j], 0, 0, 0);
    }

    float bb[4];
#pragma unroll
    for (int j = 0; j < 4; ++j)
        bb[j] = ACT ? bias[w * 64 + j * 16 + lr] : 0.f;

#pragma unroll
    for (int j = 0; j < 4; ++j) {
        const int colb = (w * 64 + j * 16 + lr) * 2;
#pragma unroll
        for (int i = 0; i < 4; ++i) {
#pragma unroll
            for (int r = 0; r < 4; ++r) {
                const int row = i * 16 + hi * 4 + r;
                float v = acc[i][j][r];
                if (ACT) {
                    v += bb[j];
                    v = v / (1.f + __expf(-v));
                }
                const int byte = row * 512 + (colb ^ ((row & 7) << 4));
                *reinterpret_cast<unsigned short*>(
                    reinterpret_cast<char*>(lout) + byte) = f2bf(v);
            }
        }
    }
}

__global__ __launch_bounds__(256) void fused_mlp_kernel(
    const float* __restrict__ summed,
    const __bf16* __restrict__ WupT, const __bf16* __restrict__ W1T,
    const __bf16* __restrict__ W2T, const __bf16* __restrict__ W3T,
    const float* __restrict__ b1, const float* __restrict__ b2,
    const float* __restrict__ b3, const float* __restrict__ Wf,
    float* __restrict__ out, int M)
{
    __shared__ __align__(16) unsigned short buf0[64 * 256];
    __shared__ __align__(16) unsigned short buf1[64 * 256];

    const int tid = threadIdx.x;
    const int l = tid & 63, w = tid >> 6;
    const int row0 = blockIdx.x * 64;

#pragma unroll
    for (int i = 0; i < 8; ++i) {
        const int id = tid + i * 256;
        const int row = id >> 5;
        const int c = (id & 31) * 4;
        float4 v = make_float4(0.f, 0.f, 0.f, 0.f);
        const int gr = row0 + row;
        if (gr < M)
            v = *reinterpret_cast<const float4*>(summed + (long long)gr * EMBED + c);
        ushort4 u = make_ushort4(f2bf(v.x), f2bf(v.y), f2bf(v.z), f2bf(v.w));
        const int byte = row * 512 + ((c * 2) ^ ((row & 7) << 4));
        *reinterpret_cast<ushort4*>(reinterpret_cast<char*>(buf0) + byte) = u;
    }
    __syncthreads();

    mlp_layer<EMBED, false>(buf0, buf1, WupT, nullptr, l, w);
    __syncthreads();
    mlp_layer<OUTE, true>(buf1, buf0, W1T, b1, l, w);
    __syncthreads();
    mlp_layer<OUTE, true>(buf0, buf1, W2T, b2, l, w);
    __syncthreads();
    mlp_layer<OUTE, true>(buf1, buf0, W3T, b3, l, w);
    __syncthreads();

    const int row = tid >> 2, q = tid & 3;
    float s = 0.f;
#pragma unroll
    for (int c = 0; c < 8; ++c) {
        const int k = q * 64 + c * 8;
        const int byte = row * 512 + ((k * 2) ^ ((row & 7) << 4));
        const bf16x8 hv = *reinterpret_cast<const bf16x8*>(
            reinterpret_cast<const char*>(buf0) + byte);
        const float4 wa = *reinterpret_cast<const float4*>(Wf + k);
        const float4 wb = *reinterpret_cast<const float4*>(Wf + k + 4);
        s += (float)hv[0] * wa.x + (float)hv[1] * wa.y +
             (float)hv[2] * wa.z + (float)hv[3] * wa.w +
             (float)hv[4] * wb.x + (float)hv[5] * wb.y +
             (float)hv[6] * wb.z + (float)hv[7] * wb.w;
    }
    s += __shfl_xor(s, 1);
    s += __shfl_xor(s, 2);
    if (q == 0 && row0 + row < M) out[row0 + row] = s;
}

extern "C" void kernel_launch(void* const* d_in, const int* in_sizes, int n_in,
                              void* d_out, int out_size, void* d_ws, size_t ws_size,
                              hipStream_t stream)
{
    const float* messages = (const float*)d_in[0];
    const float* rbf      = (const float*)d_in[1];
    const int*   idx_i    = (const int*)d_in[2];
    // d_in[3] = idx_j (unused)
    const float* W_rbf    = (const float*)d_in[4];
    const float* W_up     = (const float*)d_in[5];
    const float* W1       = (const float*)d_in[6];
    const float* b1       = (const float*)d_in[7];
    const float* W2       = (const float*)d_in[8];
    const float* b2       = (const float*)d_in[9];
    const float* W3       = (const float*)d_in[10];
    const float* b3       = (const float*)d_in[11];
    const float* Wf       = (const float*)d_in[12];
    float* out = (float*)d_out;

    const int n_edges = in_sizes[2];
    const int M = out_size;

    char* ws = (char*)d_ws;
    size_t off = 0;
    float* summed = (float*)(ws + off); off += (size_t)M * EMBED * sizeof(float);
    int* counts     = (int*)(ws + off); off += (size_t)M * sizeof(int);
    int* cursor     = (int*)(ws + off); off += (size_t)M * sizeof(int);
    int* edge_order = (int*)(ws + off); off += (size_t)n_edges * sizeof(int);
    off = (off + 255) & ~(size_t)255;
    __bf16* WupT = (__bf16*)(ws + off); off += (size_t)OUTE * EMBED * 2;
    __bf16* W1T  = (__bf16*)(ws + off); off += (size_t)OUTE * OUTE * 2;
    __bf16* W2T  = (__bf16*)(ws + off); off += (size_t)OUTE * OUTE * 2;
    __bf16* W3T  = (__bf16*)(ws + off); off += (size_t)OUTE * OUTE * 2;

    hipMemsetAsync(counts, 0, (size_t)M * sizeof(int), stream);
    hist_kernel<<<4096, 256, 0, stream>>>(idx_i, counts, n_edges);
    scan_kernel<<<1, 1024, 0, stream>>>(counts, cursor, M);
    scatter_ids_kernel<<<4096, 256, 0, stream>>>(idx_i, cursor, edge_order, n_edges);
    prep_weights_kernel<<<896, 256, 0, stream>>>(W_up, W1, W2, W3, WupT, W1T, W2T, W3T);
    gather_reduce_kernel<<<2048, 256, 0, stream>>>(messages, rbf, edge_order, counts,
                                                   cursor, W_rbf, summed, M);
    fused_mlp_kernel<<<(M + 63) / 64, 256, 0, stream>>>(summed, WupT, W1T, W2T, W3T,
                                                        b1, b2, b3, Wf, out, M);
}